// Round 6
// baseline (551.729 us; speedup 1.0000x reference)
//
#include <hip/hip_runtime.h>
#include <cstdint>
#include <cstddef>

// Problem constants (B=2, S=4096 -> T=8192 tokens)
#define T_TOK 8192
#define DIM   1024   // D
#define NE    8      // experts
#define FF    2048   // F
#define TOPK  2

typedef __bf16 bf16x8 __attribute__((ext_vector_type(8)));
typedef float  floatx4 __attribute__((ext_vector_type(4)));

__device__ __forceinline__ unsigned short f2bf(float f) {
  unsigned int u = __float_as_uint(f);
  unsigned int r = 0x7FFFu + ((u >> 16) & 1u);   // round-to-nearest-even
  return (unsigned short)((u + r) >> 16);
}

__device__ __forceinline__ void gl_lds16(const void* g, void* l) {
  __builtin_amdgcn_global_load_lds(
      (__attribute__((address_space(1))) void*)g,
      (__attribute__((address_space(3))) void*)l,
      16, 0, 0);
}

// ---------------------------------------------------------------------------
// Fused transpose + f32->bf16 for BOTH weights, 64x64 tiles, vectorized:
// float4 global loads (16B/lane), ushort4 global stores (8B/lane).
// z<8 : w1 [e][D][F] -> w1t [e][F][D]   (R=DIM, C=FF)
// z>=8: w2 [e][F][D] -> w2t [e][D][F]   (R=FF, C=DIM)
// Both are 512 64x64 tiles per expert -> uniform grid (512, 1, 16).
// LDS pitch 68 ushorts: read-phase conflicts <=2-way (free, m136).
// ---------------------------------------------------------------------------
__global__ __launch_bounds__(256) void transpose2_bf16_kernel(
    const float* __restrict__ w1, unsigned short* __restrict__ w1t,
    const float* __restrict__ w2, unsigned short* __restrict__ w2t)
{
  __shared__ unsigned short tile[64][68];   // 8.5 KB
  int z = blockIdx.z;
  int e = z & 7, sel = z >> 3;
  int R = sel ? FF : DIM;
  int C = sel ? DIM : FF;
  const float* inp = (sel ? w2 : w1) + (size_t)e * R * C;
  unsigned short* op = (sel ? w2t : w1t) + (size_t)e * R * C;
  int nc = C >> 6;                       // 64-col tiles along C
  int bx = blockIdx.x;
  int c0 = (bx % nc) * 64, r0 = (bx / nc) * 64;
  int t4 = threadIdx.x & 15, ry = threadIdx.x >> 4;   // 16 x 16
  #pragma unroll
  for (int p = 0; p < 4; ++p) {
    int r = ry + p * 16;
    float4 v = *(const float4*)&inp[(size_t)(r0 + r) * C + c0 + t4 * 4];
    ushort4 sv;
    sv.x = f2bf(v.x); sv.y = f2bf(v.y); sv.z = f2bf(v.z); sv.w = f2bf(v.w);
    *(ushort4*)&tile[r][t4 * 4] = sv;
  }
  __syncthreads();
  #pragma unroll
  for (int p = 0; p < 4; ++p) {
    int cy = ry + p * 16;
    ushort4 s;
    s.x = tile[t4 * 4 + 0][cy];
    s.y = tile[t4 * 4 + 1][cy];
    s.z = tile[t4 * 4 + 2][cy];
    s.w = tile[t4 * 4 + 3][cy];
    *(ushort4*)&op[(size_t)(c0 + cy) * R + r0 + t4 * 4] = s;
  }
}

// ---------------------------------------------------------------------------
// Gating pass 1: one wave per token (4 waves/block). gw staged TRANSPOSED in
// LDS. f64 logit accumulation (top-2 robust vs np ref). Fused x->bf16.
// Block 0 zeroes cnt[]; every block zeroes its 16KB slice of out[] (for the
// atomic-combine in gemm2; stream-ordered before gemm2 runs).
// ---------------------------------------------------------------------------
__global__ __launch_bounds__(256) void gate_kernel(
    const float* __restrict__ x, const float* __restrict__ gw,
    unsigned short* __restrict__ xb, int* __restrict__ tokExp,
    float* __restrict__ tokW, int* __restrict__ cnt,
    float* __restrict__ out)
{
  __shared__ float gwT[NE][DIM];   // 32 KB
  int tid = threadIdx.x;
  if (blockIdx.x == 0 && tid < NE) cnt[tid] = 0;
  // zero 16 KB of out: 2048 blocks x 1024 float4 = 33.5 MB
  {
    float4 z4 = make_float4(0.f, 0.f, 0.f, 0.f);
    float4* ob = (float4*)out + (size_t)blockIdx.x * 1024;
    #pragma unroll
    for (int i = 0; i < 4; ++i) ob[i * 256 + tid] = z4;
  }
  for (int i = tid; i < DIM * NE; i += 256) {
    int d = i >> 3, e = i & 7;
    gwT[e][d] = gw[i];
  }
  __syncthreads();

  int wv = tid >> 6, lane = tid & 63;
  int t = blockIdx.x * 4 + wv;
  const float* xrow = x + (size_t)t * DIM;
  unsigned short* xbrow = xb + (size_t)t * DIM;

  double acc[NE];
  for (int e = 0; e < NE; ++e) acc[e] = 0.0;

  for (int j = 0; j < 4; ++j) {
    float4 xv = ((const float4*)xrow)[j * 64 + lane];
    ushort4 s;
    s.x = f2bf(xv.x); s.y = f2bf(xv.y); s.z = f2bf(xv.z); s.w = f2bf(xv.w);
    ((ushort4*)xbrow)[j * 64 + lane] = s;
    double xd0 = (double)xv.x, xd1 = (double)xv.y;
    double xd2 = (double)xv.z, xd3 = (double)xv.w;
    for (int e = 0; e < NE; ++e) {
      float4 g = ((const float4*)&gwT[e][0])[j * 64 + lane];
      acc[e] += xd0 * (double)g.x + xd1 * (double)g.y +
                xd2 * (double)g.z + xd3 * (double)g.w;
    }
  }

  for (int s = 32; s > 0; s >>= 1)
    for (int e = 0; e < NE; ++e)
      acc[e] += __shfl_down(acc[e], s, 64);

  if (lane == 0) {
    int e0 = 0; double v0 = acc[0];
    for (int e = 1; e < NE; ++e) if (acc[e] > v0) { v0 = acc[e]; e0 = e; }
    int e1 = -1; double v1 = -1.0e300;
    for (int e = 0; e < NE; ++e) {
      if (e == e0) continue;
      if (acc[e] > v1) { v1 = acc[e]; e1 = e; }
    }
    float a = (float)v0, b = (float)v1;
    float eb = __expf(b - a);
    float den = 1.0f + eb;
    tokExp[t] = e0 | (e1 << 8);
    tokW[2 * t + 0] = 1.0f / den;
    tokW[2 * t + 1] = eb / den;
  }
}

// ---------------------------------------------------------------------------
// Gating pass 2 (PARALLEL): ballot ranks + ONE atomicAdd per expert per wave.
// Also scatters the per-slot combine weight tokW2[e][slot] so gemm2 can fuse
// the combine. Slot order nondeterministic but output bitwise invariant.
// ---------------------------------------------------------------------------
__global__ __launch_bounds__(256) void assign_kernel(
    const int* __restrict__ tokExp, const float* __restrict__ tokW,
    int* __restrict__ tIdx, float* __restrict__ tokW2, int* __restrict__ cnt)
{
  int t = blockIdx.x * 256 + threadIdx.x;
  int lane = threadIdx.x & 63;
  unsigned long long below = (1ull << lane) - 1ull;
  int enc = tokExp[t];
  int e0 = enc & 0xFF, e1 = (enc >> 8) & 0xFF;
  int s0 = 0, s1 = 0;
  for (int e = 0; e < NE; ++e) {
    unsigned long long m0 = __ballot(e0 == e);
    unsigned long long m1 = __ballot(e1 == e);
    int c0 = __popcll(m0), c1 = __popcll(m1);
    int base = 0;
    if (lane == 0 && (c0 + c1) > 0)
      base = atomicAdd(&cnt[e], c0 + c1);
    base = __shfl(base, 0, 64);
    if (e0 == e) s0 = base + __popcll(m0 & below);
    if (e1 == e) s1 = base + c0 + __popcll(m1 & below);
  }
  tIdx[e0 * T_TOK + s0] = t;
  tIdx[e1 * T_TOK + s1] = t;
  tokW2[e0 * T_TOK + s0] = tokW[2 * t + 0];
  tokW2[e1 * T_TOK + s1] = tokW[2 * t + 1];
}

// ---------------------------------------------------------------------------
// GEMM1: h[row][f] = silu( sum_d xb[tok(row)][d] * w1t[e][f][d] )   (bf16 out)
// ROUND-0 PROVEN STRUCTURE: 128x128 tile, BK=64, single-buffer 2-barrier
// K-loop, 32 KB LDS, 4 blocks/CU -> cross-block overlap hides load latency.
// XCD-pinned 1-D launch: g&7 = XCD = expert; L2 set = 2MB B-half + A-tile.
// ---------------------------------------------------------------------------
__global__ __launch_bounds__(256, 4) void gemm1_kernel(
    const unsigned short* __restrict__ xb,   // [T][D] bf16
    const unsigned short* __restrict__ w1t,  // [E][F][D] bf16
    unsigned short* __restrict__ h,          // [2T][F] bf16 (compacted)
    const int* __restrict__ tIdx, const int* __restrict__ cnt)
{
  // decode swizzled 1-D id: g = (phase*512 + m*8 + nl)*8 + e
  int g = blockIdx.x;
  int e = g & 7;
  int b = g >> 3;              // 0..1023
  int phase = b >> 9;          // 0..1  (n-half)
  int m = (b >> 3) & 63;       // 0..63 (M-tile)
  int nl = b & 7;              // 0..7  (n within half)
  int count = cnt[e];
  int r0 = m * 128;
  if (r0 >= count) return;
  int n0 = (phase * 8 + nl) * 128;

  __shared__ __align__(16) unsigned short As[8][128][8];   // 16 KB
  __shared__ __align__(16) unsigned short Bs[8][128][8];   // 16 KB

  int tid = threadIdx.x, lane = tid & 63, w = tid >> 6;
  int wr = w >> 1, wc = w & 1;
  int quad = lane >> 4, li = lane & 15;

  const unsigned short* ag[2];
  const unsigned short* bg[2];
  for (int c = 0; c < 2; ++c) {
    int mm = c * 64 + lane;
    int r = r0 + mm; if (r > count - 1) r = count - 1;
    ag[c] = xb + (size_t)tIdx[e * T_TOK + r] * DIM;
    bg[c] = w1t + ((size_t)e * FF + (n0 + mm)) * DIM;
  }

  floatx4 acc[4][4];
  for (int mi = 0; mi < 4; ++mi)
    for (int ni = 0; ni < 4; ++ni)
      for (int q = 0; q < 4; ++q) acc[mi][ni][q] = 0.0f;

  for (int k0 = 0; k0 < DIM; k0 += 64) {
    __syncthreads();
    for (int kk = 0; kk < 2; ++kk) {
      int kq = w + kk * 4;
      gl_lds16(ag[0] + k0 + kq * 8, &As[kq][0][0]);
      gl_lds16(ag[1] + k0 + kq * 8, &As[kq][64][0]);
      gl_lds16(bg[0] + k0 + kq * 8, &Bs[kq][0][0]);
      gl_lds16(bg[1] + k0 + kq * 8, &Bs[kq][64][0]);
    }
    __syncthreads();
    for (int ks = 0; ks < 2; ++ks) {
      bf16x8 af[4], bf[4];
      for (int mi = 0; mi < 4; ++mi)
        af[mi] = *(const bf16x8*)&As[ks * 4 + quad][wr * 64 + mi * 16 + li][0];
      for (int ni = 0; ni < 4; ++ni)
        bf[ni] = *(const bf16x8*)&Bs[ks * 4 + quad][wc * 64 + ni * 16 + li][0];
      for (int mi = 0; mi < 4; ++mi)
        for (int ni = 0; ni < 4; ++ni)
          acc[mi][ni] = __builtin_amdgcn_mfma_f32_16x16x32_bf16(
              af[mi], bf[ni], acc[mi][ni], 0, 0, 0);
    }
  }

  size_t hb = 0;
  for (int i = 0; i < e; ++i) hb += cnt[i];
  for (int mi = 0; mi < 4; ++mi) {
    int rowb = wr * 64 + mi * 16 + quad * 4;
    for (int rr = 0; rr < 4; ++rr) {
      int r = r0 + rowb + rr;
      if (r >= count) continue;
      unsigned short* hrow = h + (hb + r) * FF + n0 + wc * 64 + li;
      for (int ni = 0; ni < 4; ++ni) {
        float v = acc[mi][ni][rr];
        float s = v / (1.0f + __expf(-v));   // silu
        hrow[ni * 16] = f2bf(s);
      }
    }
  }
}

// ---------------------------------------------------------------------------
// GEMM2 + FUSED COMBINE: out[t][d] += tokW2[e][row] * (h[row]·w2t[e][d])
// Same round-0 GEMM core. Epilogue scatters weighted f32 via atomicAdd.
// Exactly TWO contributions per out element and 2-addend float addition is
// commutative -> bitwise deterministic. out pre-zeroed by gate_kernel.
// Eliminates yv (67MB write + 67MB read) and the combine kernel.
// ---------------------------------------------------------------------------
__global__ __launch_bounds__(256, 4) void gemm2_kernel(
    const unsigned short* __restrict__ h,    // [2T][F] bf16
    const unsigned short* __restrict__ w2t,  // [E][D][F] bf16
    float* out,                              // [T][D] f32 (atomic accumulate)
    const int* __restrict__ tIdx, const float* __restrict__ tokW2,
    const int* __restrict__ cnt)
{
  // decode swizzled 1-D id: g = (phase*256 + m*4 + nl)*8 + e
  int g = blockIdx.x;
  int e = g & 7;
  int b = g >> 3;              // 0..511
  int phase = b >> 8;          // 0..1
  int m = (b >> 2) & 63;       // 0..63
  int nl = b & 3;              // 0..3
  int count = cnt[e];
  int r0 = m * 128;
  if (r0 >= count) return;
  int n0 = (phase * 4 + nl) * 128;

  __shared__ __align__(16) unsigned short As[8][128][8];   // 16 KB
  __shared__ __align__(16) unsigned short Bs[8][128][8];   // 16 KB

  int tid = threadIdx.x, lane = tid & 63, w = tid >> 6;
  int wr = w >> 1, wc = w & 1;
  int quad = lane >> 4, li = lane & 15;
  size_t yb = 0;
  for (int i = 0; i < e; ++i) yb += cnt[i];

  const unsigned short* ag[2];
  const unsigned short* bg[2];
  for (int c = 0; c < 2; ++c) {
    int mm = c * 64 + lane;
    int r = r0 + mm; if (r > count - 1) r = count - 1;
    ag[c] = h + (yb + r) * FF;
    bg[c] = w2t + ((size_t)e * DIM + (n0 + mm)) * FF;
  }

  floatx4 acc[4][4];
  for (int mi = 0; mi < 4; ++mi)
    for (int ni = 0; ni < 4; ++ni)
      for (int q = 0; q < 4; ++q) acc[mi][ni][q] = 0.0f;

  for (int k0 = 0; k0 < FF; k0 += 64) {
    __syncthreads();
    for (int kk = 0; kk < 2; ++kk) {
      int kq = w + kk * 4;
      gl_lds16(ag[0] + k0 + kq * 8, &As[kq][0][0]);
      gl_lds16(ag[1] + k0 + kq * 8, &As[kq][64][0]);
      gl_lds16(bg[0] + k0 + kq * 8, &Bs[kq][0][0]);
      gl_lds16(bg[1] + k0 + kq * 8, &Bs[kq][64][0]);
    }
    __syncthreads();
    for (int ks = 0; ks < 2; ++ks) {
      bf16x8 af[4], bf[4];
      for (int mi = 0; mi < 4; ++mi)
        af[mi] = *(const bf16x8*)&As[ks * 4 + quad][wr * 64 + mi * 16 + li][0];
      for (int ni = 0; ni < 4; ++ni)
        bf[ni] = *(const bf16x8*)&Bs[ks * 4 + quad][wc * 64 + ni * 16 + li][0];
      for (int mi = 0; mi < 4; ++mi)
        for (int ni = 0; ni < 4; ++ni)
          acc[mi][ni] = __builtin_amdgcn_mfma_f32_16x16x32_bf16(
              af[mi], bf[ni], acc[mi][ni], 0, 0, 0);
    }
  }

  for (int mi = 0; mi < 4; ++mi) {
    int rowb = wr * 64 + mi * 16 + quad * 4;
    for (int rr = 0; rr < 4; ++rr) {
      int r = r0 + rowb + rr;
      if (r >= count) continue;
      int t = tIdx[e * T_TOK + r];
      float wgt = tokW2[e * T_TOK + r];
      float* orow = out + (size_t)t * DIM + n0 + wc * 64 + li;
      for (int ni = 0; ni < 4; ++ni)
        atomicAdd(&orow[ni * 16], wgt * acc[mi][ni][rr]);
    }
  }
}

// ---------------------------------------------------------------------------
extern "C" void kernel_launch(void* const* d_in, const int* in_sizes, int n_in,
                              void* d_out, int out_size, void* d_ws, size_t ws_size,
                              hipStream_t stream)
{
  const float* x  = (const float*)d_in[0];   // [T][D]
  const float* gw = (const float*)d_in[1];   // [D][E]
  const float* w1 = (const float*)d_in[2];   // [E][D][F]
  const float* w2 = (const float*)d_in[3];   // [E][F][D]
  float* out = (float*)d_out;                // [T][D]

  // workspace carve-up (256B aligned)
  size_t o = 0;
  auto alloc = [&](size_t bytes) {
    void* p = (char*)d_ws + o;
    o += (bytes + 255) & ~(size_t)255;
    return p;
  };
  unsigned short* xb   = (unsigned short*)alloc((size_t)T_TOK * DIM * 2);      // 16.8 MB
  unsigned short* w1t  = (unsigned short*)alloc((size_t)NE * DIM * FF * 2);    // 33.6 MB
  unsigned short* w2t  = (unsigned short*)alloc((size_t)NE * DIM * FF * 2);    // 33.6 MB
  unsigned short* hbuf = (unsigned short*)alloc((size_t)T_TOK * TOPK * FF * 2);// 67.1 MB
  int*   tIdx   = (int*)alloc((size_t)NE * T_TOK * 4);
  float* tokW2  = (float*)alloc((size_t)NE * T_TOK * 4);
  float* tokW   = (float*)alloc((size_t)2 * T_TOK * 4);
  int*   tokExp = (int*)alloc((size_t)T_TOK * 4);
  int*   cnt    = (int*)alloc((size_t)NE * 4);

  // both weight transposes in ONE launch (z = expert | sel<<3), 64x64 tiles
  transpose2_bf16_kernel<<<dim3(512, 1, 2 * NE), 256, 0, stream>>>(w1, w1t, w2, w2t);

  gate_kernel<<<T_TOK / 4, 256, 0, stream>>>(x, gw, xb, tokExp, tokW, cnt, out);
  assign_kernel<<<T_TOK / 256, 256, 0, stream>>>(tokExp, tokW, tIdx, tokW2, cnt);

  // XCD-pinned swizzled 1-D grids (g & 7 = XCD = expert)
  gemm1_kernel<<<8192, 256, 0, stream>>>(xb, w1t, hbuf, tIdx, cnt);
  gemm2_kernel<<<4096, 256, 0, stream>>>(hbuf, w2t, out, tIdx, tokW2, cnt);
}